// Round 1
// 452.204 us; speedup vs baseline: 1.1500x; 1.1500x over previous
//
#include <hip/hip_runtime.h>
#include <hip/hip_bf16.h>

// LightGCN: final = (ego + A·ego + A²·ego + A³·ego) / 4
// CSR build per call: hist + scan, then TWO-PHASE scatter:
//   bin_edges:     LDS-staged bucket binning (bucket = 1024 rows), coalesced run writes
//   bucket_scatter: per-bucket exact CSR placement via LDS row cursors (L2-local writes)
// Gather SpMM: bf16 features, 8 lanes/row (16B loads), unroll-2 dual-accumulator.
// Final combine reads ego + h1..h3 once.

#define NUM_USERS 100000
#define NUM_ITEMS 200000
#define NN (NUM_USERS + NUM_ITEMS)
#define DIM 64
#define BROWS 1024                       // rows per bucket
#define NB_BUCKETS ((NN + BROWS - 1) / BROWS)   // 293
#define CHUNK 4096                       // edges per bin_edges block
#define RK 16                            // reg-staged entries/thread in bucket_scatter (512*16 = 8192)
#define OVF 4096                         // LDS overflow entries in bucket_scatter

typedef unsigned short ushort8_t __attribute__((ext_vector_type(8)));

__device__ __forceinline__ float bf16_to_f32(unsigned short u) {
    return __uint_as_float(((unsigned int)u) << 16);
}
__device__ __forceinline__ unsigned short f32_to_bf16(float f) {
    unsigned int u = __float_as_uint(f);
    u += 0x7fffu + ((u >> 16) & 1u);   // round-to-nearest-even
    return (unsigned short)(u >> 16);
}

// ---------------- zero an int array ----------------
__global__ void zero_ints(int* __restrict__ p, int n) {
    int i = blockIdx.x * blockDim.x + threadIdx.x;
    if (i < n) p[i] = 0;
}

// ---------------- histogram of row indices ----------------
__global__ void hist_kernel(const int* __restrict__ rows, int* __restrict__ counts, int E) {
    int e = blockIdx.x * blockDim.x + threadIdx.x;
    if (e < E) atomicAdd(&counts[rows[e]], 1);
}

// ---------------- scan pass 1: per-block (1024 elems) partial sums ----------------
__global__ void scan_partials(const int* __restrict__ counts, int* __restrict__ blocksums, int n) {
    __shared__ int lds[256];
    int tid = threadIdx.x;
    int base = blockIdx.x * 1024 + tid * 4;
    int s = 0;
#pragma unroll
    for (int k = 0; k < 4; ++k) { int idx = base + k; if (idx < n) s += counts[idx]; }
    lds[tid] = s;
    __syncthreads();
    for (int off = 128; off > 0; off >>= 1) {
        if (tid < off) lds[tid] += lds[tid + off];
        __syncthreads();
    }
    if (tid == 0) blocksums[blockIdx.x] = lds[0];
}

// ---------------- scan pass 2: exclusive scan of block sums (one block) ----------
__global__ void scan_blocksums_par(int* __restrict__ blocksums, int nb,
                                   int* __restrict__ row_start, int n) {
    __shared__ int lds[512];
    int t = threadIdx.x;
    int v = (t < nb) ? blocksums[t] : 0;
    lds[t] = v;
    __syncthreads();
    for (int off = 1; off < 512; off <<= 1) {
        int u = (t >= off) ? lds[t - off] : 0;
        __syncthreads();
        lds[t] += u;
        __syncthreads();
    }
    if (t < nb) blocksums[t] = lds[t] - v;     // exclusive
    if (t == 0) row_start[n] = lds[nb - 1];    // total = E
}

// ---------------- scan pass 3: block-local exclusive scan + write ----------------
__global__ void scan_write(int* __restrict__ counts, const int* __restrict__ blocksums,
                           int* __restrict__ cursor, int n) {
    __shared__ int lds[256];
    int tid = threadIdx.x;
    int base = blockIdx.x * 1024 + tid * 4;
    int local[4]; int tsum = 0;
#pragma unroll
    for (int k = 0; k < 4; ++k) {
        int idx = base + k;
        local[k] = (idx < n) ? counts[idx] : 0;
        tsum += local[k];
    }
    lds[tid] = tsum;
    __syncthreads();
    for (int off = 1; off < 256; off <<= 1) {
        int v = 0;
        if (tid >= off) v = lds[tid - off];
        __syncthreads();
        lds[tid] += v;
        __syncthreads();
    }
    int run = lds[tid] - tsum + blocksums[blockIdx.x];
#pragma unroll
    for (int k = 0; k < 4; ++k) {
        int idx = base + k;
        if (idx < n) { counts[idx] = run; cursor[idx] = run; run += local[k]; }
    }
}

// ---------------- init bucket cursors from row_start ----------------
__global__ void init_bcur(const int* __restrict__ row_start, int* __restrict__ bcur) {
    int b = threadIdx.x;
    if (b < NB_BUCKETS) bcur[b] = row_start[b << 10];
}

// ---------------- phase A: LDS-staged bucket binning ----------------
// Bucket = row >> 10 (1024 rows). Each block: 4096 edges -> LDS hist -> LDS scan ->
// reserve global ranges (1 atomic per block-bucket) -> reorder in LDS -> contiguous
// run writes (avg run 14 edges = 112B). Packs (col | rowlocal<<19, valbits) in 8B.
__global__ __launch_bounds__(512) void bin_edges(const int* __restrict__ rows,
                                                 const int* __restrict__ cols,
                                                 const float* __restrict__ vals,
                                                 int* __restrict__ bcur,
                                                 uint2* __restrict__ epack, int E) {
    __shared__ int lcnt[512];
    __shared__ int lscan[512];
    __shared__ int lcur[512];
    __shared__ int gbase[512];
    __shared__ uint2 stage[CHUNK];
    __shared__ int dstg[CHUNK];

    int t = threadIdx.x;
    int base = blockIdx.x * CHUNK;
    int n = E - base; if (n > CHUNK) n = CHUNK;

    lcnt[t] = 0;
    __syncthreads();

    int r[8], c[8], b[8];
    unsigned int vb[8];
    int ebase = base + t * 8;
    if (ebase + 8 <= E) {
        int4 r0 = *(const int4*)(rows + ebase);
        int4 r1 = *(const int4*)(rows + ebase + 4);
        int4 c0 = *(const int4*)(cols + ebase);
        int4 c1 = *(const int4*)(cols + ebase + 4);
        float4 v0 = *(const float4*)(vals + ebase);
        float4 v1 = *(const float4*)(vals + ebase + 4);
        r[0]=r0.x; r[1]=r0.y; r[2]=r0.z; r[3]=r0.w; r[4]=r1.x; r[5]=r1.y; r[6]=r1.z; r[7]=r1.w;
        c[0]=c0.x; c[1]=c0.y; c[2]=c0.z; c[3]=c0.w; c[4]=c1.x; c[5]=c1.y; c[6]=c1.z; c[7]=c1.w;
        vb[0]=__float_as_uint(v0.x); vb[1]=__float_as_uint(v0.y);
        vb[2]=__float_as_uint(v0.z); vb[3]=__float_as_uint(v0.w);
        vb[4]=__float_as_uint(v1.x); vb[5]=__float_as_uint(v1.y);
        vb[6]=__float_as_uint(v1.z); vb[7]=__float_as_uint(v1.w);
#pragma unroll
        for (int k = 0; k < 8; ++k) b[k] = r[k] >> 10;
    } else {
#pragma unroll
        for (int k = 0; k < 8; ++k) {
            int e = ebase + k;
            if (e < E) { r[k] = rows[e]; c[k] = cols[e]; vb[k] = __float_as_uint(vals[e]); b[k] = r[k] >> 10; }
            else b[k] = -1;
        }
    }
#pragma unroll
    for (int k = 0; k < 8; ++k)
        if (b[k] >= 0) atomicAdd(&lcnt[b[k]], 1);
    __syncthreads();

    // Hillis-Steele inclusive scan over 512 entries
    int val = lcnt[t];
    lscan[t] = val;
    __syncthreads();
    for (int off = 1; off < 512; off <<= 1) {
        int u = (t >= off) ? lscan[t - off] : 0;
        __syncthreads();
        lscan[t] += u;
        __syncthreads();
    }
    int excl = lscan[t] - val;
    lscan[t] = excl;          // exclusive local base (own-slot rewrite, no cross reads until sync)
    lcur[t]  = excl;
    if (t < NB_BUCKETS && val > 0)
        gbase[t] = atomicAdd(&bcur[t], val);
    __syncthreads();

    // reorder into LDS (sorted by bucket), record global dst per slot
#pragma unroll
    for (int k = 0; k < 8; ++k) {
        int bb = b[k];
        if (bb >= 0) {
            int l = atomicAdd(&lcur[bb], 1);
            unsigned int w0 = (unsigned int)c[k] | (((unsigned int)(r[k] & (BROWS - 1))) << 19);
            stage[l] = make_uint2(w0, vb[k]);
            dstg[l] = gbase[bb] + (l - lscan[bb]);
        }
    }
    __syncthreads();

    // coalesced run writes
    for (int l = t; l < n; l += 512)
        epack[dstg[l]] = stage[l];
}

// ---------------- phase B: per-bucket exact CSR placement ----------------
// One block per bucket (~6.8K edges, ~55KB region). Load whole bucket into regs
// (+LDS overflow), then scatter to final positions via LDS row cursors. All writes
// hit a ~55KB L2-resident region within the block lifetime -> no write amplification.
__global__ __launch_bounds__(512) void bucket_scatter(const int* __restrict__ row_start,
                                                      uint2* __restrict__ epack) {
    __shared__ int cur[BROWS];
    __shared__ uint2 ovf[OVF];
    int b = blockIdx.x;
    int t = threadIdx.x;
    int rbase = b << 10;
    int rend = rbase + BROWS; if (rend > NN) rend = NN;
    int s = row_start[rbase];
    int e = row_start[rend];
    int cnt = e - s;

    for (int r = t; r < rend - rbase; r += 512)
        cur[r] = row_start[rbase + r];

    uint2 p[RK];
#pragma unroll
    for (int k = 0; k < RK; ++k) {
        int idx = t + k * 512;            // 0..8191
        if (s + idx < e) p[k] = epack[s + idx];
    }
    for (int l = 8192 + t; l < cnt && l < 8192 + OVF; l += 512)
        ovf[l - 8192] = epack[s + l];
    __syncthreads();

#pragma unroll
    for (int k = 0; k < RK; ++k) {
        int idx = t + k * 512;
        if (s + idx < e) {
            uint2 w = p[k];
            int rl = (w.x >> 19) & (BROWS - 1);
            int pp = atomicAdd(&cur[rl], 1);
            epack[pp] = make_uint2(w.x & 0x7FFFFu, w.y);
        }
    }
    for (int l = 8192 + t; l < cnt && l < 8192 + OVF; l += 512) {
        uint2 w = ovf[l - 8192];
        int rl = (w.x >> 19) & (BROWS - 1);
        int pp = atomicAdd(&cur[rl], 1);
        epack[pp] = make_uint2(w.x & 0x7FFFFu, w.y);
    }
}

// ---------------- init: h0 = ego (bf16) ----------------
__global__ void init_h0(const float4* __restrict__ user4,
                        const float4* __restrict__ item4,
                        ushort4* __restrict__ h4,
                        int total4, int user4n) {
    int i = blockIdx.x * blockDim.x + threadIdx.x;
    if (i >= total4) return;
    float4 v = (i < user4n) ? user4[i] : item4[i - user4n];
    ushort4 b;
    b.x = f32_to_bf16(v.x); b.y = f32_to_bf16(v.y);
    b.z = f32_to_bf16(v.z); b.w = f32_to_bf16(v.w);
    h4[i] = b;
}

// ---------------- gather SpMM: y = A * x (bf16 in/out, f32 acc) --------------
// 8 lanes/row, 16B ushort8 loads, unroll-2 with dual accumulators.
__global__ void spmm_gather(const int* __restrict__ row_start,
                            const float2* __restrict__ epack,
                            const unsigned short* __restrict__ x,
                            unsigned short* __restrict__ y) {
    int tid = threadIdx.x;
    int sub = tid >> 3;          // 0..31 rows per block
    int lane = tid & 7;          // 8 lanes per row, 8 bf16 each
    int row = blockIdx.x * 32 + sub;
    if (row >= NN) return;
    int s = row_start[row];
    int e = row_start[row + 1];
    int off = lane << 3;         // element offset within row

    float a0[8], a1[8];
#pragma unroll
    for (int k = 0; k < 8; ++k) { a0[k] = 0.f; a1[k] = 0.f; }

    int j = s;
    for (; j + 1 < e; j += 2) {
        float2 e0 = epack[j];
        float2 e1 = epack[j + 1];
        int c0 = __float_as_int(e0.x);
        int c1 = __float_as_int(e1.x);
        ushort8_t x0 = *(const ushort8_t*)(x + c0 * DIM + off);
        ushort8_t x1 = *(const ushort8_t*)(x + c1 * DIM + off);
        float v0 = e0.y, v1 = e1.y;
#pragma unroll
        for (int k = 0; k < 8; ++k) a0[k] += v0 * bf16_to_f32(x0[k]);
#pragma unroll
        for (int k = 0; k < 8; ++k) a1[k] += v1 * bf16_to_f32(x1[k]);
    }
    if (j < e) {
        float2 e0 = epack[j];
        int c0 = __float_as_int(e0.x);
        ushort8_t x0 = *(const ushort8_t*)(x + c0 * DIM + off);
        float v0 = e0.y;
#pragma unroll
        for (int k = 0; k < 8; ++k) a0[k] += v0 * bf16_to_f32(x0[k]);
    }

    ushort8_t yb;
#pragma unroll
    for (int k = 0; k < 8; ++k) yb[k] = f32_to_bf16(a0[k] + a1[k]);
    *(ushort8_t*)(y + row * DIM + off) = yb;
}

// ---------------- final: out = (ego + h1 + h2 + h3) * 0.25 ----------------
__global__ void final_combine(const float4* __restrict__ user4,
                              const float4* __restrict__ item4,
                              const ushort4* __restrict__ h1,
                              const ushort4* __restrict__ h2,
                              const ushort4* __restrict__ h3,
                              float4* __restrict__ out4,
                              int total4, int user4n) {
    int i = blockIdx.x * blockDim.x + threadIdx.x;
    if (i >= total4) return;
    float4 ego = (i < user4n) ? user4[i] : item4[i - user4n];
    ushort4 a = h1[i], b = h2[i], c = h3[i];
    float4 o;
    o.x = (ego.x + bf16_to_f32(a.x) + bf16_to_f32(b.x) + bf16_to_f32(c.x)) * 0.25f;
    o.y = (ego.y + bf16_to_f32(a.y) + bf16_to_f32(b.y) + bf16_to_f32(c.y)) * 0.25f;
    o.z = (ego.z + bf16_to_f32(a.z) + bf16_to_f32(b.z) + bf16_to_f32(c.z)) * 0.25f;
    o.w = (ego.w + bf16_to_f32(a.w) + bf16_to_f32(b.w) + bf16_to_f32(c.w)) * 0.25f;
    out4[i] = o;
}

extern "C" void kernel_launch(void* const* d_in, const int* in_sizes, int n_in,
                              void* d_out, int out_size, void* d_ws, size_t ws_size,
                              hipStream_t stream) {
    const float* user_emb = (const float*)d_in[0];
    const float* item_emb = (const float*)d_in[1];
    const int*   adj_rows = (const int*)d_in[2];
    const int*   adj_cols = (const int*)d_in[3];
    const float* adj_vals = (const float*)d_in[4];
    float* out = (float*)d_out;

    const int E = in_sizes[2];
    const int total = NN * DIM;            // 19.2M elems
    const int total4 = total / 4;          // 4.8M
    const int user4n = NUM_USERS * DIM / 4;

    // workspace layout (8B-aligned first)
    float2* epack = (float2*)d_ws;                         // E float2 (16 MB)
    unsigned short* hA = (unsigned short*)(epack + E);     // total bf16 (h0, then h3)
    unsigned short* hB = hA + total;                       // total bf16 (h1)
    unsigned short* hC = hB + total;                       // total bf16 (h2)
    int* row_start = (int*)(hC + total);                   // NN+1 ints
    int* cursor    = row_start + NN + 1;                   // NN+1 ints (reused as bucket cursors)
    int* blocksums = cursor + NN + 1;                      // scan partials

    const int TB = 256;
    const int gridV = (total4 + TB - 1) / TB;
    const int gridN = (NN + 1 + TB - 1) / TB;
    const int gridE = (E + TB - 1) / TB;
    const int nScan = (NN + 1023) / 1024;            // 293
    const int gridG = (NN + 31) / 32;                // 9375
    const int nChunksA = (E + CHUNK - 1) / CHUNK;    // 489

    // ---- CSR build ----
    zero_ints<<<gridN, TB, 0, stream>>>(row_start, NN + 1);
    hist_kernel<<<gridE, TB, 0, stream>>>(adj_rows, row_start, E);
    scan_partials<<<nScan, TB, 0, stream>>>(row_start, blocksums, NN);
    scan_blocksums_par<<<1, 512, 0, stream>>>(blocksums, nScan, row_start, NN);
    scan_write<<<nScan, TB, 0, stream>>>(row_start, blocksums, cursor, NN);
    init_bcur<<<1, 512, 0, stream>>>(row_start, cursor);
    bin_edges<<<nChunksA, 512, 0, stream>>>(adj_rows, adj_cols, adj_vals, cursor,
                                            (uint2*)epack, E);
    bucket_scatter<<<NB_BUCKETS, 512, 0, stream>>>(row_start, (uint2*)epack);

    // ---- init h0 ----
    init_h0<<<gridV, TB, 0, stream>>>((const float4*)user_emb, (const float4*)item_emb,
                                      (ushort4*)hA, total4, user4n);

    // ---- 3 gather SpMM layers ----
    spmm_gather<<<gridG, TB, 0, stream>>>(row_start, epack, hA, hB); // h1 = A*h0
    spmm_gather<<<gridG, TB, 0, stream>>>(row_start, epack, hB, hC); // h2 = A*h1
    spmm_gather<<<gridG, TB, 0, stream>>>(row_start, epack, hC, hA); // h3 = A*h2

    // ---- final combine ----
    final_combine<<<gridV, TB, 0, stream>>>((const float4*)user_emb, (const float4*)item_emb,
                                            (const ushort4*)hB, (const ushort4*)hC,
                                            (const ushort4*)hA, (float4*)out,
                                            total4, user4n);
}

// Round 2
// 383.899 us; speedup vs baseline: 1.3546x; 1.1779x over previous
//
#include <hip/hip_runtime.h>
#include <hip/hip_bf16.h>

// LightGCN: final = (ego + A·ego + A²·ego + A³·ego) / 4
// CSR build per call, NO per-row global histogram:
//   bucket_hist:    LDS hist of 293 coarse buckets (1024 rows each), 1 pass over rows
//   scan_buckets:   1-block scan -> bucket CSR bases (bbase) + bin cursors (bcur)
//   bin_edges:      LDS-staged bucket binning, coalesced run writes (packs rowlocal in col bits)
//   bucket_scatter: per-bucket LDS row-histogram + scan -> writes row_start AND places
//                   edges at exact CSR positions (all writes L2-local, no amplification)
// Gather SpMM: bf16 features, 8 lanes/row (16B loads), unroll-2 dual-accumulator.
// Final combine reads ego + h1..h3 once.

#define NUM_USERS 100000
#define NUM_ITEMS 200000
#define NN (NUM_USERS + NUM_ITEMS)
#define DIM 64
#define BROWS 1024                              // rows per bucket
#define NB_BUCKETS ((NN + BROWS - 1) / BROWS)   // 293
#define CHUNK 4096                              // edges per binning block
#define RK 16                                   // reg-staged entries/thread (512*16 = 8192)
#define OVF 4096                                // LDS overflow entries in bucket_scatter

typedef unsigned short ushort8_t __attribute__((ext_vector_type(8)));

__device__ __forceinline__ float bf16_to_f32(unsigned short u) {
    return __uint_as_float(((unsigned int)u) << 16);
}
__device__ __forceinline__ unsigned short f32_to_bf16(float f) {
    unsigned int u = __float_as_uint(f);
    u += 0x7fffu + ((u >> 16) & 1u);   // round-to-nearest-even
    return (unsigned short)(u >> 16);
}

// ---------------- zero an int array ----------------
__global__ void zero_ints(int* __restrict__ p, int n) {
    int i = blockIdx.x * blockDim.x + threadIdx.x;
    if (i < n) p[i] = 0;
}

// ---------------- coarse bucket histogram (293 buckets) ----------------
__global__ __launch_bounds__(512) void bucket_hist(const int* __restrict__ rows,
                                                   int* __restrict__ bcnt, int E) {
    __shared__ int h[512];
    int t = threadIdx.x;
    h[t] = 0;
    __syncthreads();
    int base = blockIdx.x * CHUNK + t * 8;
    if (base + 8 <= E) {
        int4 r0 = *(const int4*)(rows + base);
        int4 r1 = *(const int4*)(rows + base + 4);
        atomicAdd(&h[r0.x >> 10], 1); atomicAdd(&h[r0.y >> 10], 1);
        atomicAdd(&h[r0.z >> 10], 1); atomicAdd(&h[r0.w >> 10], 1);
        atomicAdd(&h[r1.x >> 10], 1); atomicAdd(&h[r1.y >> 10], 1);
        atomicAdd(&h[r1.z >> 10], 1); atomicAdd(&h[r1.w >> 10], 1);
    } else {
        for (int k = 0; k < 8; ++k) {
            int e = base + k;
            if (e < E) atomicAdd(&h[rows[e] >> 10], 1);
        }
    }
    __syncthreads();
    if (t < NB_BUCKETS && h[t] > 0) atomicAdd(&bcnt[t], h[t]);
}

// ---------------- scan bucket counts -> bases; init cursors ----------------
__global__ void scan_buckets(const int* __restrict__ bcnt, int* __restrict__ bbase,
                             int* __restrict__ bcur, int* __restrict__ row_start, int E) {
    __shared__ int lds[512];
    int t = threadIdx.x;
    int v = bcnt[t];               // zeroed beyond NB_BUCKETS
    lds[t] = v;
    __syncthreads();
    for (int off = 1; off < 512; off <<= 1) {
        int u = (t >= off) ? lds[t - off] : 0;
        __syncthreads();
        lds[t] += u;
        __syncthreads();
    }
    int base = lds[t] - v;         // exclusive scan
    if (t <= NB_BUCKETS) bbase[t] = base;   // bbase[NB_BUCKETS] == E
    if (t < NB_BUCKETS)  bcur[t] = base;
    if (t == 0) row_start[NN] = E;
}

// ---------------- phase A: LDS-staged bucket binning ----------------
// Bucket = row >> 10. Each block: 4096 edges -> LDS hist -> LDS scan -> reserve global
// ranges (1 atomic per block-bucket) -> reorder in LDS -> contiguous run writes.
// Packs (col | rowlocal<<19, valbits) in 8B.
__global__ __launch_bounds__(512) void bin_edges(const int* __restrict__ rows,
                                                 const int* __restrict__ cols,
                                                 const float* __restrict__ vals,
                                                 int* __restrict__ bcur,
                                                 uint2* __restrict__ epack, int E) {
    __shared__ int lcnt[512];
    __shared__ int lscan[512];
    __shared__ int lcur[512];
    __shared__ int gbase[512];
    __shared__ uint2 stage[CHUNK];
    __shared__ int dstg[CHUNK];

    int t = threadIdx.x;
    int base = blockIdx.x * CHUNK;
    int n = E - base; if (n > CHUNK) n = CHUNK;

    lcnt[t] = 0;
    __syncthreads();

    int r[8], c[8], b[8];
    unsigned int vb[8];
    int ebase = base + t * 8;
    if (ebase + 8 <= E) {
        int4 r0 = *(const int4*)(rows + ebase);
        int4 r1 = *(const int4*)(rows + ebase + 4);
        int4 c0 = *(const int4*)(cols + ebase);
        int4 c1 = *(const int4*)(cols + ebase + 4);
        float4 v0 = *(const float4*)(vals + ebase);
        float4 v1 = *(const float4*)(vals + ebase + 4);
        r[0]=r0.x; r[1]=r0.y; r[2]=r0.z; r[3]=r0.w; r[4]=r1.x; r[5]=r1.y; r[6]=r1.z; r[7]=r1.w;
        c[0]=c0.x; c[1]=c0.y; c[2]=c0.z; c[3]=c0.w; c[4]=c1.x; c[5]=c1.y; c[6]=c1.z; c[7]=c1.w;
        vb[0]=__float_as_uint(v0.x); vb[1]=__float_as_uint(v0.y);
        vb[2]=__float_as_uint(v0.z); vb[3]=__float_as_uint(v0.w);
        vb[4]=__float_as_uint(v1.x); vb[5]=__float_as_uint(v1.y);
        vb[6]=__float_as_uint(v1.z); vb[7]=__float_as_uint(v1.w);
#pragma unroll
        for (int k = 0; k < 8; ++k) b[k] = r[k] >> 10;
    } else {
#pragma unroll
        for (int k = 0; k < 8; ++k) {
            int e = ebase + k;
            if (e < E) { r[k] = rows[e]; c[k] = cols[e]; vb[k] = __float_as_uint(vals[e]); b[k] = r[k] >> 10; }
            else b[k] = -1;
        }
    }
#pragma unroll
    for (int k = 0; k < 8; ++k)
        if (b[k] >= 0) atomicAdd(&lcnt[b[k]], 1);
    __syncthreads();

    // Hillis-Steele inclusive scan over 512 entries
    int val = lcnt[t];
    lscan[t] = val;
    __syncthreads();
    for (int off = 1; off < 512; off <<= 1) {
        int u = (t >= off) ? lscan[t - off] : 0;
        __syncthreads();
        lscan[t] += u;
        __syncthreads();
    }
    int excl = lscan[t] - val;
    lscan[t] = excl;          // exclusive local base (own-slot rewrite)
    lcur[t]  = excl;
    if (t < NB_BUCKETS && val > 0)
        gbase[t] = atomicAdd(&bcur[t], val);
    __syncthreads();

    // reorder into LDS (sorted by bucket), record global dst per slot
#pragma unroll
    for (int k = 0; k < 8; ++k) {
        int bb = b[k];
        if (bb >= 0) {
            int l = atomicAdd(&lcur[bb], 1);
            unsigned int w0 = (unsigned int)c[k] | (((unsigned int)(r[k] & (BROWS - 1))) << 19);
            stage[l] = make_uint2(w0, vb[k]);
            dstg[l] = gbase[bb] + (l - lscan[bb]);
        }
    }
    __syncthreads();

    // coalesced run writes
    for (int l = t; l < n; l += 512)
        epack[dstg[l]] = stage[l];
}

// ---------------- phase B: per-bucket row-hist + scan + exact CSR placement ----
// One block per bucket (~6.8K edges, ~55KB region). Load whole bucket into regs
// (+LDS overflow), LDS-histogram the 1024 rowlocals, LDS-scan -> row_start for this
// bucket, then scatter to final positions via LDS row cursors. All epack writes hit
// a ~55KB L2-resident region within the block lifetime -> no write amplification.
__global__ __launch_bounds__(512) void bucket_scatter(const int* __restrict__ bbase,
                                                      int* __restrict__ row_start,
                                                      uint2* __restrict__ epack) {
    __shared__ int cur[BROWS];     // hist -> cursor
    __shared__ int stmp[512];
    __shared__ uint2 ovf[OVF];
    int b = blockIdx.x;
    int t = threadIdx.x;
    int rbase = b << 10;
    int nrows = NN - rbase; if (nrows > BROWS) nrows = BROWS;
    int s = bbase[b];
    int e = bbase[b + 1];
    int cnt = e - s;

    cur[t] = 0; cur[t + 512] = 0;
    __syncthreads();

    uint2 p[RK];
#pragma unroll
    for (int k = 0; k < RK; ++k) {
        int idx = t + k * 512;     // 0..8191
        if (idx < cnt) {
            p[k] = epack[s + idx];
            atomicAdd(&cur[(p[k].x >> 19) & (BROWS - 1)], 1);
        }
    }
    for (int l = 8192 + t; l < cnt && l < 8192 + OVF; l += 512) {
        uint2 w = epack[s + l];
        ovf[l - 8192] = w;
        atomicAdd(&cur[(w.x >> 19) & (BROWS - 1)], 1);
    }
    __syncthreads();

    // exclusive scan of cur[0..1023], 2 elems/thread
    int c0 = cur[2 * t], c1 = cur[2 * t + 1];
    int ps = c0 + c1;
    stmp[t] = ps;
    __syncthreads();
    for (int off = 1; off < 512; off <<= 1) {
        int u = (t >= off) ? stmp[t - off] : 0;
        __syncthreads();
        stmp[t] += u;
        __syncthreads();
    }
    int pexcl = stmp[t] - ps;      // exclusive over pair sums
    int b0 = s + pexcl;
    int b1 = b0 + c0;
    cur[2 * t] = b0;
    cur[2 * t + 1] = b1;
    if (2 * t < nrows)     row_start[rbase + 2 * t]     = b0;
    if (2 * t + 1 < nrows) row_start[rbase + 2 * t + 1] = b1;
    __syncthreads();

#pragma unroll
    for (int k = 0; k < RK; ++k) {
        int idx = t + k * 512;
        if (idx < cnt) {
            uint2 w = p[k];
            int rl = (w.x >> 19) & (BROWS - 1);
            int pp = atomicAdd(&cur[rl], 1);
            epack[pp] = make_uint2(w.x & 0x7FFFFu, w.y);
        }
    }
    for (int l = 8192 + t; l < cnt && l < 8192 + OVF; l += 512) {
        uint2 w = ovf[l - 8192];
        int rl = (w.x >> 19) & (BROWS - 1);
        int pp = atomicAdd(&cur[rl], 1);
        epack[pp] = make_uint2(w.x & 0x7FFFFu, w.y);
    }
}

// ---------------- init: h0 = ego (bf16) ----------------
__global__ void init_h0(const float4* __restrict__ user4,
                        const float4* __restrict__ item4,
                        ushort4* __restrict__ h4,
                        int total4, int user4n) {
    int i = blockIdx.x * blockDim.x + threadIdx.x;
    if (i >= total4) return;
    float4 v = (i < user4n) ? user4[i] : item4[i - user4n];
    ushort4 b;
    b.x = f32_to_bf16(v.x); b.y = f32_to_bf16(v.y);
    b.z = f32_to_bf16(v.z); b.w = f32_to_bf16(v.w);
    h4[i] = b;
}

// ---------------- gather SpMM: y = A * x (bf16 in/out, f32 acc) --------------
// 8 lanes/row, 16B ushort8 loads, unroll-2 with dual accumulators.
__global__ void spmm_gather(const int* __restrict__ row_start,
                            const float2* __restrict__ epack,
                            const unsigned short* __restrict__ x,
                            unsigned short* __restrict__ y) {
    int tid = threadIdx.x;
    int sub = tid >> 3;          // 0..31 rows per block
    int lane = tid & 7;          // 8 lanes per row, 8 bf16 each
    int row = blockIdx.x * 32 + sub;
    if (row >= NN) return;
    int s = row_start[row];
    int e = row_start[row + 1];
    int off = lane << 3;         // element offset within row

    float a0[8], a1[8];
#pragma unroll
    for (int k = 0; k < 8; ++k) { a0[k] = 0.f; a1[k] = 0.f; }

    int j = s;
    for (; j + 1 < e; j += 2) {
        float2 e0 = epack[j];
        float2 e1 = epack[j + 1];
        int c0 = __float_as_int(e0.x);
        int c1 = __float_as_int(e1.x);
        ushort8_t x0 = *(const ushort8_t*)(x + c0 * DIM + off);
        ushort8_t x1 = *(const ushort8_t*)(x + c1 * DIM + off);
        float v0 = e0.y, v1 = e1.y;
#pragma unroll
        for (int k = 0; k < 8; ++k) a0[k] += v0 * bf16_to_f32(x0[k]);
#pragma unroll
        for (int k = 0; k < 8; ++k) a1[k] += v1 * bf16_to_f32(x1[k]);
    }
    if (j < e) {
        float2 e0 = epack[j];
        int c0 = __float_as_int(e0.x);
        ushort8_t x0 = *(const ushort8_t*)(x + c0 * DIM + off);
        float v0 = e0.y;
#pragma unroll
        for (int k = 0; k < 8; ++k) a0[k] += v0 * bf16_to_f32(x0[k]);
    }

    ushort8_t yb;
#pragma unroll
    for (int k = 0; k < 8; ++k) yb[k] = f32_to_bf16(a0[k] + a1[k]);
    *(ushort8_t*)(y + row * DIM + off) = yb;
}

// ---------------- final: out = (ego + h1 + h2 + h3) * 0.25 ----------------
__global__ void final_combine(const float4* __restrict__ user4,
                              const float4* __restrict__ item4,
                              const ushort4* __restrict__ h1,
                              const ushort4* __restrict__ h2,
                              const ushort4* __restrict__ h3,
                              float4* __restrict__ out4,
                              int total4, int user4n) {
    int i = blockIdx.x * blockDim.x + threadIdx.x;
    if (i >= total4) return;
    float4 ego = (i < user4n) ? user4[i] : item4[i - user4n];
    ushort4 a = h1[i], b = h2[i], c = h3[i];
    float4 o;
    o.x = (ego.x + bf16_to_f32(a.x) + bf16_to_f32(b.x) + bf16_to_f32(c.x)) * 0.25f;
    o.y = (ego.y + bf16_to_f32(a.y) + bf16_to_f32(b.y) + bf16_to_f32(c.y)) * 0.25f;
    o.z = (ego.z + bf16_to_f32(a.z) + bf16_to_f32(b.z) + bf16_to_f32(c.z)) * 0.25f;
    o.w = (ego.w + bf16_to_f32(a.w) + bf16_to_f32(b.w) + bf16_to_f32(c.w)) * 0.25f;
    out4[i] = o;
}

extern "C" void kernel_launch(void* const* d_in, const int* in_sizes, int n_in,
                              void* d_out, int out_size, void* d_ws, size_t ws_size,
                              hipStream_t stream) {
    const float* user_emb = (const float*)d_in[0];
    const float* item_emb = (const float*)d_in[1];
    const int*   adj_rows = (const int*)d_in[2];
    const int*   adj_cols = (const int*)d_in[3];
    const float* adj_vals = (const float*)d_in[4];
    float* out = (float*)d_out;

    const int E = in_sizes[2];
    const int total = NN * DIM;            // 19.2M elems
    const int total4 = total / 4;          // 4.8M
    const int user4n = NUM_USERS * DIM / 4;

    // workspace layout (8B-aligned first)
    float2* epack = (float2*)d_ws;                         // E float2 (16 MB)
    unsigned short* hA = (unsigned short*)(epack + E);     // total bf16 (h0, then h3)
    unsigned short* hB = hA + total;                       // total bf16 (h1)
    unsigned short* hC = hB + total;                       // total bf16 (h2)
    int* row_start = (int*)(hC + total);                   // NN+1 ints
    int* bcnt  = row_start + NN + 1;                       // 512 ints
    int* bbase = bcnt + 512;                               // 512 ints
    int* bcur  = bbase + 512;                              // 512 ints

    const int TB = 256;
    const int gridV = (total4 + TB - 1) / TB;
    const int gridG = (NN + 31) / 32;                // 9375
    const int nChunksA = (E + CHUNK - 1) / CHUNK;    // 489

    // ---- CSR build ----
    zero_ints<<<1, 512, 0, stream>>>(bcnt, 512);
    bucket_hist<<<nChunksA, 512, 0, stream>>>(adj_rows, bcnt, E);
    scan_buckets<<<1, 512, 0, stream>>>(bcnt, bbase, bcur, row_start, E);
    bin_edges<<<nChunksA, 512, 0, stream>>>(adj_rows, adj_cols, adj_vals, bcur,
                                            (uint2*)epack, E);
    bucket_scatter<<<NB_BUCKETS, 512, 0, stream>>>(bbase, row_start, (uint2*)epack);

    // ---- init h0 ----
    init_h0<<<gridV, TB, 0, stream>>>((const float4*)user_emb, (const float4*)item_emb,
                                      (ushort4*)hA, total4, user4n);

    // ---- 3 gather SpMM layers ----
    spmm_gather<<<gridG, TB, 0, stream>>>(row_start, epack, hA, hB); // h1 = A*h0
    spmm_gather<<<gridG, TB, 0, stream>>>(row_start, epack, hB, hC); // h2 = A*h1
    spmm_gather<<<gridG, TB, 0, stream>>>(row_start, epack, hC, hA); // h3 = A*h2

    // ---- final combine ----
    final_combine<<<gridV, TB, 0, stream>>>((const float4*)user_emb, (const float4*)item_emb,
                                            (const ushort4*)hB, (const ushort4*)hC,
                                            (const ushort4*)hA, (float4*)out,
                                            total4, user4n);
}